// Round 8
// baseline (477.318 us; speedup 1.0000x reference)
//
#include <hip/hip_runtime.h>

#define NH   12
#define ND   64
#define NSEQ 4096
#define NIT  16
#define MM   256   // rows per iteration chunk
#define ES   4     // e-slices per (b,h) chain (W columns are independent)
#define EW   16    // e-columns per block
#define NHD  (NH*ND)

// LDS pitches (bf16 elems). Per quarter-wave slot analysis: all reads/writes <=2-way.
#define T_P  264
#define W_P  72

typedef __bf16 bf16_t;
typedef bf16_t bf16x8 __attribute__((ext_vector_type(8)));
typedef float  f32x4  __attribute__((ext_vector_type(4)));

static __device__ __forceinline__ unsigned short f2bf(float f) {
    union { float f; unsigned u; } v; v.f = f;
    return (unsigned short)((v.u + 0x7FFFu + ((v.u >> 16) & 1u)) >> 16);
}

static __device__ __forceinline__ bf16x8 pack8(float4 a, float4 b) {
    union { unsigned short u[8]; bf16x8 v; } r;
    r.u[0] = f2bf(a.x); r.u[1] = f2bf(a.y); r.u[2] = f2bf(a.z); r.u[3] = f2bf(a.w);
    r.u[4] = f2bf(b.x); r.u[5] = f2bf(b.y); r.u[6] = f2bf(b.z); r.u[7] = f2bf(b.w);
    return r.v;
}

// Barrier draining ONLY LDS ops; global loads/stores stay in flight across it.
static __device__ __forceinline__ void barrier_lds() {
    asm volatile("s_waitcnt lgkmcnt(0)" ::: "memory");
    __builtin_amdgcn_s_barrier();
    asm volatile("" ::: "memory");
}

extern "C" __global__ void __launch_bounds__(256)
ttt_fused(const float* __restrict__ qg, const float* __restrict__ kg,
          const float* __restrict__ vg, const float* __restrict__ Wi,
          float* __restrict__ outg)
{
    // 44544 B static LDS -> 3 blocks/CU (12 waves), VGPR budget ~168 (R6 mechanism)
    __shared__ unsigned short XT[64 * T_P];   // x_tr transposed [d][m]
    __shared__ unsigned short ET[EW * T_P];   // err [e][m]
    __shared__ unsigned short WBT[EW * W_P];  // W slice transposed [e][d]

    const int tid  = threadIdx.x;
    const int lane = tid & 63;
    const int wv   = tid >> 6;      // wave 0..3
    const int g    = lane >> 4;     // 0..3
    const int ln   = lane & 15;     // 0..15

    const int nbh = 192;            // B*H
    const int bid = blockIdx.x;
    const int bh  = bid % nbh;      // siblings (same bh) are 192 apart -> same XCD
    const int es  = bid / nbh;      // e-slice 0..3
    const int b   = bh / NH;
    const int h   = bh - b * NH;

    const float* kb   = kg + (size_t)bh * NSEQ * ND;
    const float* qb   = qg + (size_t)bh * NSEQ * ND;
    const float* vcol = vg + (size_t)bh * NSEQ * ND + es * EW;
    float* ob = outg + (size_t)b * NSEQ * NHD + h * ND + es * EW;

    const int r0 = wv << 6;         // wave's 64-row m-slice (A and C)
    const int d0 = wv << 4;         // wave's 16-row d-slice (B)
    const float scale = 1.0f / 16384.0f;   // LR / (m*D)

    // staging ownership: thread -> m-row pair (2tp, 2tp+1) x d-half [dh, dh+32)
    const int tp = tid & 127;
    const int dh = (tid >> 7) << 5;

    // ---- prologue: issue chunk-0 globals
    float4 ks[16];
    {
        const float* kr = kb + (size_t)(tp * 2) * ND + dh;
        #pragma unroll
        for (int i = 0; i < 8; ++i) {
            ks[i]     = *(const float4*)(kr + 4 * i);
            ks[8 + i] = *(const float4*)(kr + ND + 4 * i);
        }
    }
    float vq[16];
    {
        const float* vp = vcol + (size_t)r0 * ND;
        #pragma unroll
        for (int ms = 0; ms < 4; ++ms)
            #pragma unroll
            for (int j = 0; j < 4; ++j)
                vq[ms * 4 + j] = vp[(size_t)(ms * 16 + g * 4 + j) * ND + ln];
    }
    float wf[4];   // wave-private f32 master: wf[j] = W[d0+4g+j][es*16+ln]
    {
        const float* wp = Wi + (size_t)h * ND * ND;
        ushort4 wq; unsigned short* wqp = (unsigned short*)&wq;
        #pragma unroll
        for (int j = 0; j < 4; ++j) {
            wf[j] = wp[(size_t)(d0 + g * 4 + j) * ND + es * EW + ln];
            wqp[j] = f2bf(wf[j]);
        }
        *(ushort4*)&WBT[ln * W_P + d0 + g * 4] = wq;
    }
    // stage XT(0)
    #pragma unroll
    for (int i = 0; i < 8; ++i)
        #pragma unroll
        for (int j = 0; j < 4; ++j) {
            unsigned pk = (unsigned)f2bf(((const float*)&ks[i])[j]) |
                          ((unsigned)f2bf(((const float*)&ks[8 + i])[j]) << 16);
            *(unsigned*)&XT[(dh + i * 4 + j) * T_P + tp * 2] = pk;
        }
    barrier_lds();   // XT(0), WBT(W_0) visible

    for (int it = 0; it < NIT; ++it) {
        // ================= region 1: stage XT(it) | A(it) | C(it-1) =================
        if (it > 0) {
            #pragma unroll
            for (int i = 0; i < 8; ++i)
                #pragma unroll
                for (int j = 0; j < 4; ++j) {
                    unsigned pk = (unsigned)f2bf(((const float*)&ks[i])[j]) |
                                  ((unsigned)f2bf(((const float*)&ks[8 + i])[j]) << 16);
                    *(unsigned*)&XT[(dh + i * 4 + j) * T_P + tp * 2] = pk;
                }
        }

        // W fragment (W_it): B-operand for both A and C
        bf16x8 w0 = *(const bf16x8*)&WBT[ln * W_P + g * 8];
        bf16x8 w1 = *(const bf16x8*)&WBT[ln * W_P + 32 + g * 8];

        // A(it): err[m][e] = x W - y -> ET  (x frags from global, L2-hot; 1-subtile lookahead)
        {
            const float* xp = kb + ((size_t)(it * MM) + r0 + ln) * ND;
            float4 xf0 = *(const float4*)(xp + g * 8);
            float4 xf1 = *(const float4*)(xp + g * 8 + 4);
            float4 xf2 = *(const float4*)(xp + 32 + g * 8);
            float4 xf3 = *(const float4*)(xp + 32 + g * 8 + 4);
            #pragma unroll
            for (int ms = 0; ms < 4; ++ms) {
                float4 xn0, xn1, xn2, xn3;
                if (ms < 3) {
                    const float* xn = xp + (size_t)(ms + 1) * 16 * ND;
                    xn0 = *(const float4*)(xn + g * 8);
                    xn1 = *(const float4*)(xn + g * 8 + 4);
                    xn2 = *(const float4*)(xn + 32 + g * 8);
                    xn3 = *(const float4*)(xn + 32 + g * 8 + 4);
                }
                bf16x8 xa0 = pack8(xf0, xf1);
                bf16x8 xa1 = pack8(xf2, xf3);
                f32x4 ae = {0.f, 0.f, 0.f, 0.f};
                ae = __builtin_amdgcn_mfma_f32_16x16x32_bf16(xa0, w0, ae, 0, 0, 0);
                ae = __builtin_amdgcn_mfma_f32_16x16x32_bf16(xa1, w1, ae, 0, 0, 0);
                ushort4 ew; unsigned short* ewp = (unsigned short*)&ew;
                ewp[0] = f2bf(ae[0] - vq[ms * 4 + 0]);
                ewp[1] = f2bf(ae[1] - vq[ms * 4 + 1]);
                ewp[2] = f2bf(ae[2] - vq[ms * 4 + 2]);
                ewp[3] = f2bf(ae[3] - vq[ms * 4 + 3]);
                *(ushort4*)&ET[ln * T_P + r0 + ms * 16 + g * 4] = ew;
                xf0 = xn0; xf1 = xn1; xf2 = xn2; xf3 = xn3;
            }
        }

        // C(it-1): out = x_te W_it (same w0/w1 fragment; q frags transient)
        if (it > 0) {
            const float* qp = qb + ((size_t)((it - 1) * MM) + r0 + ln) * ND;
            float4 qf0 = *(const float4*)(qp + g * 8);
            float4 qf1 = *(const float4*)(qp + g * 8 + 4);
            float4 qf2 = *(const float4*)(qp + 32 + g * 8);
            float4 qf3 = *(const float4*)(qp + 32 + g * 8 + 4);
            #pragma unroll
            for (int ms = 0; ms < 4; ++ms) {
                float4 qn0, qn1, qn2, qn3;
                if (ms < 3) {
                    const float* qn = qp + (size_t)(ms + 1) * 16 * ND;
                    qn0 = *(const float4*)(qn + g * 8);
                    qn1 = *(const float4*)(qn + g * 8 + 4);
                    qn2 = *(const float4*)(qn + 32 + g * 8);
                    qn3 = *(const float4*)(qn + 32 + g * 8 + 4);
                }
                bf16x8 a0 = pack8(qf0, qf1);
                bf16x8 a1 = pack8(qf2, qf3);
                f32x4 oc = {0.f, 0.f, 0.f, 0.f};
                oc = __builtin_amdgcn_mfma_f32_16x16x32_bf16(a0, w0, oc, 0, 0, 0);
                oc = __builtin_amdgcn_mfma_f32_16x16x32_bf16(a1, w1, oc, 0, 0, 0);
                #pragma unroll
                for (int j = 0; j < 4; ++j)
                    ob[((size_t)((it - 1) * MM) + r0 + ms * 16 + g * 4 + j) * NHD + ln] = oc[j];
                qf0 = qn0; qf1 = qn1; qf2 = qn2; qf3 = qn3;
            }
        }

        barrier_lds();   // alpha: XT(it), ET(it) visible

        // ================= region 2: prefetch(it+1) | B(it) =================
        if (it + 1 < NIT) {
            const float* kr = kb + ((size_t)((it + 1) * MM) + tp * 2) * ND + dh;
            #pragma unroll
            for (int i = 0; i < 8; ++i) {
                ks[i]     = *(const float4*)(kr + 4 * i);
                ks[8 + i] = *(const float4*)(kr + ND + 4 * i);
            }
            const float* vp = vcol + ((size_t)((it + 1) * MM) + r0) * ND;
            #pragma unroll
            for (int ms = 0; ms < 4; ++ms)
                #pragma unroll
                for (int j = 0; j < 4; ++j)
                    vq[ms * 4 + j] = vp[(size_t)(ms * 16 + g * 4 + j) * ND + ln];
        }

        // B(it): grad[d][e] = x^T err ; wf -= scale*grad ; WBT <- W_{it+1}
        {
            f32x4 ga = {0.f, 0.f, 0.f, 0.f};
            #pragma unroll
            for (int kx = 0; kx < 8; ++kx) {
                bf16x8 af  = *(const bf16x8*)&XT[(d0 + ln) * T_P + kx * 32 + g * 8];
                bf16x8 bf_ = *(const bf16x8*)&ET[ln * T_P + kx * 32 + g * 8];
                ga = __builtin_amdgcn_mfma_f32_16x16x32_bf16(af, bf_, ga, 0, 0, 0);
            }
            ushort4 wq; unsigned short* wqp = (unsigned short*)&wq;
            #pragma unroll
            for (int j = 0; j < 4; ++j) {
                wf[j] -= scale * ga[j];
                wqp[j] = f2bf(wf[j]);
            }
            *(ushort4*)&WBT[ln * W_P + d0 + g * 4] = wq;
        }

        barrier_lds();   // beta: WBT(W_{it+1}) visible; XT free for overwrite
    }

    // ================= epilogue: C(NIT-1) with W_NIT =================
    {
        bf16x8 w0 = *(const bf16x8*)&WBT[ln * W_P + g * 8];
        bf16x8 w1 = *(const bf16x8*)&WBT[ln * W_P + 32 + g * 8];
        const float* qp = qb + ((size_t)((NIT - 1) * MM) + r0 + ln) * ND;
        #pragma unroll
        for (int ms = 0; ms < 4; ++ms) {
            const float* qr = qp + (size_t)ms * 16 * ND;
            float4 qf0 = *(const float4*)(qr + g * 8);
            float4 qf1 = *(const float4*)(qr + g * 8 + 4);
            float4 qf2 = *(const float4*)(qr + 32 + g * 8);
            float4 qf3 = *(const float4*)(qr + 32 + g * 8 + 4);
            bf16x8 a0 = pack8(qf0, qf1);
            bf16x8 a1 = pack8(qf2, qf3);
            f32x4 oc = {0.f, 0.f, 0.f, 0.f};
            oc = __builtin_amdgcn_mfma_f32_16x16x32_bf16(a0, w0, oc, 0, 0, 0);
            oc = __builtin_amdgcn_mfma_f32_16x16x32_bf16(a1, w1, oc, 0, 0, 0);
            #pragma unroll
            for (int j = 0; j < 4; ++j)
                ob[((size_t)((NIT - 1) * MM) + r0 + ms * 16 + g * 4 + j) * NHD + ln] = oc[j];
        }
    }
}

extern "C" void kernel_launch(void* const* d_in, const int* in_sizes, int n_in,
                              void* d_out, int out_size, void* d_ws, size_t ws_size,
                              hipStream_t stream) {
    const float* q  = (const float*)d_in[0];
    const float* k  = (const float*)d_in[1];
    const float* v  = (const float*)d_in[2];
    const float* Wi = (const float*)d_in[3];
    float* out = (float*)d_out;

    int nbh  = in_sizes[0] / (NSEQ * ND);   // 192
    int grid = nbh * ES;                    // 768 = 3 blocks/CU on 256 CUs
    hipLaunchKernelGGL(ttt_fused, dim3(grid), dim3(256), 0, stream,
                       q, k, v, Wi, out);
}

// Round 9
// 192.983 us; speedup vs baseline: 2.4734x; 2.4734x over previous
//
#include <hip/hip_runtime.h>

#define NH   12
#define ND   64
#define NSEQ 4096
#define NIT  16
#define MM   256   // rows per iteration chunk

// LDS pitches (bf16 elements)
#define X_P  72    // X row-major pitch (256 x 72)
#define T_P  264   // XT/ET pitch (64 x 264)
#define W_P  72    // WBT pitch (64 x 72)

// static LDS layout (bytes) — one block/CU: compiler budgets 128 VGPR (R6-proven)
#define SM_X    0
#define SM_XT0  36864
#define SM_XT1  70656
#define SM_ET   104448
#define SM_WBT  138240
#define SM_TOTAL 147456

typedef __bf16 bf16_t;
typedef bf16_t bf16x8 __attribute__((ext_vector_type(8)));
typedef float  f32x4  __attribute__((ext_vector_type(4)));
typedef unsigned short u16x8 __attribute__((ext_vector_type(8)));

// native cast -> v_cvt_pk_bf16_f32 (RNE), 1 VALU op vs 5-op software round
static __device__ __forceinline__ unsigned short f2bf(float f) {
    union { __bf16 h; unsigned short u; } v; v.h = (__bf16)f; return v.u;
}

static __device__ __forceinline__ bf16x8 pack8(float4 a, float4 b) {
    union { unsigned short u[8]; bf16x8 v; } r;
    r.u[0] = f2bf(a.x); r.u[1] = f2bf(a.y); r.u[2] = f2bf(a.z); r.u[3] = f2bf(a.w);
    r.u[4] = f2bf(b.x); r.u[5] = f2bf(b.y); r.u[6] = f2bf(b.z); r.u[7] = f2bf(b.w);
    return r.v;
}

// Barrier draining ONLY LDS ops; global loads/stores stay in flight across it.
static __device__ __forceinline__ void barrier_lds() {
    asm volatile("s_waitcnt lgkmcnt(0)" ::: "memory");
    __builtin_amdgcn_s_barrier();
    asm volatile("" ::: "memory");
}

extern "C" __global__ void __launch_bounds__(1024)
ttt_fused(const float* __restrict__ qg, const float* __restrict__ kg,
          const float* __restrict__ vg, const float* __restrict__ Wi,
          float* __restrict__ outg)
{
    __shared__ char smem[SM_TOTAL] __attribute__((aligned(16)));
    unsigned short* X   = (unsigned short*)(smem + SM_X);    // x_tr row-major [m][d]
    unsigned short* ET  = (unsigned short*)(smem + SM_ET);   // err transposed [e][m]
    unsigned short* WBT = (unsigned short*)(smem + SM_WBT);  // W transposed bf16 [e][d]

    const int tid  = threadIdx.x;
    const int lane = tid & 63;
    const int wv   = tid >> 6;      // wave 0..15
    const int g    = lane >> 4;     // 0..3
    const int ln   = lane & 15;     // 0..15

    const int bh = blockIdx.x;
    const int b  = bh / NH;
    const int h  = bh - b * NH;

    const float* kb = kg + (size_t)bh * NSEQ * ND;
    const float* vb = vg + (size_t)bh * NSEQ * ND;
    const float* qb = qg + (size_t)bh * NSEQ * ND;
    float* ob = outg + (size_t)b * NSEQ * (NH * ND) + h * ND;

    const int r0 = wv << 4;          // wave's 16-row m-slice (A and C)
    const int d0 = (wv >> 2) << 4;   // wave's grad tile (B)
    const int e0 = (wv & 3) << 4;
    const float scale = 1.0f / 16384.0f;  // LR / (m*D)

    // staging ownership: thread -> rows (sR, sR+1) x cols sC..sC+7
    const int sR = (tid & 127) << 1;   // 0..254, even
    const int sC = (tid >> 7) << 3;    // 0..56

    // ---- prologue: issue chunk-0 globals
    float4 ks[4], vq[4], qr[4];
    {
        const float* kr = kb + (size_t)sR * ND + sC;
        ks[0] = *(const float4*)(kr);
        ks[1] = *(const float4*)(kr + 4);
        ks[2] = *(const float4*)(kr + ND);
        ks[3] = *(const float4*)(kr + ND + 4);
        const float* vp = vb + (size_t)(r0 + ln) * ND + (g << 2);
        vq[0] = *(const float4*)(vp);
        vq[1] = *(const float4*)(vp + 16);
        vq[2] = *(const float4*)(vp + 32);
        vq[3] = *(const float4*)(vp + 48);
    }

    // ---- W_init -> wf regs (wave-private f32 master) + WBT bf16
    float wf[4];
    {
        const float* wp = Wi + (size_t)h * ND * ND;
        ushort4 wq; unsigned short* wqp = (unsigned short*)&wq;
        #pragma unroll
        for (int j = 0; j < 4; ++j) {
            wf[j] = wp[(size_t)(d0 + (g << 2) + j) * ND + e0 + ln];
            wqp[j] = f2bf(wf[j]);
        }
        *(ushort4*)&WBT[(e0 + ln) * W_P + d0 + (g << 2)] = wq;
    }

    // ---- stage chunk 0 -> X (row-major) + XT0 (transposed)
    {
        unsigned short* XTn = (unsigned short*)(smem + SM_XT0);
        union { unsigned short u[8]; u16x8 v; } lo, hi;
        #pragma unroll
        for (int j = 0; j < 8; ++j) {
            lo.u[j] = f2bf(j < 4 ? ((const float*)&ks[0])[j] : ((const float*)&ks[1])[j - 4]);
            hi.u[j] = f2bf(j < 4 ? ((const float*)&ks[2])[j] : ((const float*)&ks[3])[j - 4]);
        }
        *(u16x8*)&X[(size_t)sR * X_P + sC]       = lo.v;
        *(u16x8*)&X[(size_t)(sR + 1) * X_P + sC] = hi.v;
        #pragma unroll
        for (int j = 0; j < 8; ++j)
            *(unsigned*)&XTn[(sC + j) * T_P + sR] = (unsigned)lo.u[j] | ((unsigned)hi.u[j] << 16);
    }
    barrier_lds();   // X/XT0 (x_tr(0)), WBT (W_0) visible

    int cur = 0;
    for (int it = 0; it < NIT; ++it) {
        unsigned short* XTc = (unsigned short*)(smem + (cur ? SM_XT1 : SM_XT0));
        unsigned short* XTn = (unsigned short*)(smem + (cur ? SM_XT0 : SM_XT1));

        // ================= region 1: A(it) | C(it-1), fused per e-tile =================
        {
            bf16x8 aq0, aq1;
            if (it > 0) { aq0 = pack8(qr[0], qr[1]); aq1 = pack8(qr[2], qr[3]); }
            bf16x8 xb0 = *(const bf16x8*)&X[(r0 + ln) * X_P + (g << 3)];
            bf16x8 xb1 = *(const bf16x8*)&X[(r0 + ln) * X_P + 32 + (g << 3)];

            #pragma unroll
            for (int e = 0; e < 4; ++e) {
                // one WBT fragment read serves BOTH A (as A-operand) and C (as B-operand)
                bf16x8 w0 = *(const bf16x8*)&WBT[((e << 4) + ln) * W_P + (g << 3)];
                bf16x8 w1 = *(const bf16x8*)&WBT[((e << 4) + ln) * W_P + 32 + (g << 3)];

                // A(it): errT = W^T x_tr^T - y^T -> ET
                f32x4 acc = {0.f, 0.f, 0.f, 0.f};
                acc = __builtin_amdgcn_mfma_f32_16x16x32_bf16(w0, xb0, acc, 0, 0, 0);
                acc = __builtin_amdgcn_mfma_f32_16x16x32_bf16(w1, xb1, acc, 0, 0, 0);
                int rr = (e << 4) + (g << 2);
                ET[(rr + 0) * T_P + r0 + ln] = f2bf(acc[0] - vq[e].x);
                ET[(rr + 1) * T_P + r0 + ln] = f2bf(acc[1] - vq[e].y);
                ET[(rr + 2) * T_P + r0 + ln] = f2bf(acc[2] - vq[e].z);
                ET[(rr + 3) * T_P + r0 + ln] = f2bf(acc[3] - vq[e].w);

                // C(it-1): out = x_te * W_it (off the recurrence path)
                if (it > 0) {
                    f32x4 oc = {0.f, 0.f, 0.f, 0.f};
                    oc = __builtin_amdgcn_mfma_f32_16x16x32_bf16(aq0, w0, oc, 0, 0, 0);
                    oc = __builtin_amdgcn_mfma_f32_16x16x32_bf16(aq1, w1, oc, 0, 0, 0);
                    #pragma unroll
                    for (int j = 0; j < 4; ++j)
                        ob[((size_t)((it - 1) * MM) + r0 + (g << 2) + j) * (NH * ND) + (e << 4) + ln] = oc[j];
                }
            }
        }

        barrier_lds();   // alpha: ET(it) visible; A's X reads drained

        // ================= region 2: prefetch issues | B(it) | stage(it+1) =================
        // all global loads issued BEFORE B: latency hides under B + staging + beta
        if (it + 1 < NIT) {
            const float* kr = kb + (size_t)((it + 1) * MM + sR) * ND + sC;
            ks[0] = *(const float4*)(kr);
            ks[1] = *(const float4*)(kr + 4);
            ks[2] = *(const float4*)(kr + ND);
            ks[3] = *(const float4*)(kr + ND + 4);
            const float* vp = vb + (size_t)((it + 1) * MM + r0 + ln) * ND + (g << 2);
            vq[0] = *(const float4*)(vp);
            vq[1] = *(const float4*)(vp + 16);
            vq[2] = *(const float4*)(vp + 32);
            vq[3] = *(const float4*)(vp + 48);
        }
        {
            const float* qrow = qb + ((size_t)(it * MM) + r0 + ln) * ND;
            qr[0] = *(const float4*)(qrow + (g << 3));
            qr[1] = *(const float4*)(qrow + (g << 3) + 4);
            qr[2] = *(const float4*)(qrow + 32 + (g << 3));
            qr[3] = *(const float4*)(qrow + 32 + (g << 3) + 4);
        }

        // B(it): grad = x_tr^T err ; W -= grad/16384 ; WBT <- W_{it+1}
        {
            f32x4 ga = {0.f, 0.f, 0.f, 0.f};
            #pragma unroll
            for (int kx = 0; kx < 8; ++kx) {
                bf16x8 af  = *(const bf16x8*)&XTc[(d0 + ln) * T_P + (kx << 5) + (g << 3)];
                bf16x8 bf_ = *(const bf16x8*)&ET[(e0 + ln) * T_P + (kx << 5) + (g << 3)];
                ga = __builtin_amdgcn_mfma_f32_16x16x32_bf16(af, bf_, ga, 0, 0, 0);
            }
            ushort4 wq; unsigned short* wqp = (unsigned short*)&wq;
            #pragma unroll
            for (int j = 0; j < 4; ++j) {
                wf[j] -= scale * ga[j];
                wqp[j] = f2bf(wf[j]);
            }
            *(ushort4*)&WBT[(e0 + ln) * W_P + d0 + (g << 2)] = wq;
        }

        // stage x_tr(it+1) -> X + XT[next] (ks consumed inside region; never crosses a barrier)
        if (it + 1 < NIT) {
            union { unsigned short u[8]; u16x8 v; } lo, hi;
            #pragma unroll
            for (int j = 0; j < 8; ++j) {
                lo.u[j] = f2bf(j < 4 ? ((const float*)&ks[0])[j] : ((const float*)&ks[1])[j - 4]);
                hi.u[j] = f2bf(j < 4 ? ((const float*)&ks[2])[j] : ((const float*)&ks[3])[j - 4]);
            }
            *(u16x8*)&X[(size_t)sR * X_P + sC]       = lo.v;
            *(u16x8*)&X[(size_t)(sR + 1) * X_P + sC] = hi.v;
            #pragma unroll
            for (int j = 0; j < 8; ++j)
                *(unsigned*)&XTn[(sC + j) * T_P + sR] = (unsigned)lo.u[j] | ((unsigned)hi.u[j] << 16);
        }

        barrier_lds();   // beta: WBT(W_{it+1}), X/XT[next] (x_tr(it+1)) visible
        cur ^= 1;
    }

    // ================= epilogue: C(NIT-1) with W_NIT =================
    {
        bf16x8 a0 = pack8(qr[0], qr[1]);
        bf16x8 a1 = pack8(qr[2], qr[3]);
        #pragma unroll
        for (int e = 0; e < 4; ++e) {
            bf16x8 w0 = *(const bf16x8*)&WBT[((e << 4) + ln) * W_P + (g << 3)];
            bf16x8 w1 = *(const bf16x8*)&WBT[((e << 4) + ln) * W_P + 32 + (g << 3)];
            f32x4 oc = {0.f, 0.f, 0.f, 0.f};
            oc = __builtin_amdgcn_mfma_f32_16x16x32_bf16(a0, w0, oc, 0, 0, 0);
            oc = __builtin_amdgcn_mfma_f32_16x16x32_bf16(a1, w1, oc, 0, 0, 0);
            #pragma unroll
            for (int j = 0; j < 4; ++j)
                ob[((size_t)((NIT - 1) * MM) + r0 + (g << 2) + j) * (NH * ND) + (e << 4) + ln] = oc[j];
        }
    }
}

extern "C" void kernel_launch(void* const* d_in, const int* in_sizes, int n_in,
                              void* d_out, int out_size, void* d_ws, size_t ws_size,
                              hipStream_t stream) {
    const float* q  = (const float*)d_in[0];
    const float* k  = (const float*)d_in[1];
    const float* v  = (const float*)d_in[2];
    const float* Wi = (const float*)d_in[3];
    float* out = (float*)d_out;

    int grid = in_sizes[0] / (NSEQ * ND);   // B * H = 192
    hipLaunchKernelGGL(ttt_fused, dim3(grid), dim3(1024), 0, stream,
                       q, k, v, Wi, out);
}